// Round 10
// baseline (53.487 us; speedup 1.0000x reference)
//
#include <hip/hip_runtime.h>
#include <math.h>

#define NFR 8
#define DD 2048
#define NS 25
#define NB 64
#define NPAIR (NS*NB)          // 1600
#define NITER 32
#define WS_TGT 640000          // float offset of tgt region: 1600*4*100
#define SOLVE_BLKS 100

typedef __attribute__((ext_vector_type(8))) short short8;
typedef __attribute__((ext_vector_type(4))) float f32x4;

// Branch-free acos, ~1e-7 rel (Cephes asinf core). Valid for |x| <= 1.
__device__ __forceinline__ float acos_fast(float x) {
    const float ax = fabsf(x);
    const bool big = ax > 0.5f;
    const float z = big ? 0.5f * (1.f - ax) : x * x;
    const float s = big ? sqrtf(z) : ax;
    float p = fmaf(z, 4.2163199048e-2f, 2.4181311049e-2f);
    p = fmaf(z, p, 4.5470025998e-2f);
    p = fmaf(z, p, 7.4953002686e-2f);
    p = fmaf(z, p, 1.6666752422e-1f);
    const float asin_s = fmaf(s * z, p, s);
    const float asin_abs = big ? (1.5707963267948966f - 2.f * asin_s) : asin_s;
    return 1.5707963267948966f - copysignf(asin_abs, x);
}

// Pack hi-bf16 of (a,b) and lo-bf16 remainders via v_perm_b32.
#define SPLIT2(a, b, HI, LO) { \
    const float ha_ = __uint_as_float(__float_as_uint(a) & 0xFFFF0000u); \
    const float hb_ = __uint_as_float(__float_as_uint(b) & 0xFFFF0000u); \
    HI = __builtin_amdgcn_perm(__float_as_uint(b), __float_as_uint(a), 0x07060302u); \
    LO = __builtin_amdgcn_perm(__float_as_uint((b) - hb_), __float_as_uint((a) - ha_), 0x07060302u); \
}

// Async DMA: 64 lanes x 16B -> 1KB contiguous LDS (wave-uniform dst base).
__device__ __forceinline__ void load_lds16(const float* g, float* l) {
    __builtin_amdgcn_global_load_lds(
        (const __attribute__((address_space(1))) void*)g,
        (__attribute__((address_space(3))) void*)l, 16, 0, 0);
}

// Block = (b, kq, sg): stage tgt[b] K-quarter ONCE (16KB), stream 5 support
// sets against it through a 3-slot rotating sup buffer with depth-2 prefetch.
// Counted vmcnt (never 0 mid-loop) + raw s_barrier keep 2 stage-sets in
// flight across barriers. bf16 hi/lo MFMA Gram (verified); partials -> ws.
// Grid mapped so all 20 blocks of one b land on one XCD (tgt L2-resident).
__global__ __launch_bounds__(512) void gram_kernel(const float* __restrict__ sup,
                                                   const float* __restrict__ tgt,
                                                   float* __restrict__ ws) {
    const int bid = blockIdx.x;
    const int u   = bid >> 3;           // 0..159
    const int b   = (bid & 7) * 8 + (u & 7);
    const int u2  = u >> 3;             // 0..19
    const int kq  = u2 & 3;
    const int sg  = u2 >> 2;            // 0..4
    const int tid = threadIdx.x;
    const int wv  = tid >> 6;           // 0..7
    const int l   = tid & 63;
    const int fr  = l & 15;             // fragment row
    const int kg  = l >> 4;

    __shared__ float tbuf[8 * 512];     // 16 KB  tgt K-quarter
    __shared__ float sbuf[3][8 * 512];  // 48 KB  sup rotating slots
    __shared__ float part[8 * 272];     // 8.7 KB wave partials

    // Wave wv stages row wv of each 8x512 buffer (2 chunks of 1KB, source
    // lane-swizzled by row so the swizzled ds_read below sees linear data).
    {
        const float* g = tgt + ((size_t)b * NFR + wv) * DD + kq * 512;
        const float* gl = g + (l ^ wv) * 4;
        load_lds16(gl,       tbuf + wv * 512);
        load_lds16(gl + 256, tbuf + wv * 512 + 256);
    }
    const int s0 = sg * 5;
    {   // prologue: sup slots 0,1
        #pragma unroll
        for (int i = 0; i < 2; ++i) {
            const float* g = sup + (((size_t)(s0 + i) * NB + b) * NFR + wv) * DD + kq * 512;
            const float* gl = g + (l ^ wv) * 4;
            load_lds16(gl,       sbuf[i] + wv * 512);
            load_lds16(gl + 256, sbuf[i] + wv * 512 + 256);
        }
    }

    #pragma unroll
    for (int i = 0; i < 5; ++i) {
        if (i + 2 <= 4) {   // depth-2 prefetch into slot (i+2)%3 (free since iter i-1)
            const int sl = (i + 2) % 3;
            const float* g = sup + (((size_t)(s0 + i + 2) * NB + b) * NFR + wv) * DD + kq * 512;
            const float* gl = g + (l ^ wv) * 4;
            load_lds16(gl,       sbuf[sl] + wv * 512);
            load_lds16(gl + 256, sbuf[sl] + wv * 512 + 256);
        }
        // Counted wait: drain everything except the 2 newest stage-sets.
        if (i <= 2)      asm volatile("s_waitcnt vmcnt(4)" ::: "memory");
        else if (i == 3) asm volatile("s_waitcnt vmcnt(2)" ::: "memory");
        else             asm volatile("s_waitcnt vmcnt(0)" ::: "memory");
        __builtin_amdgcn_s_barrier();
        __builtin_amdgcn_sched_barrier(0);

        // Compute Gram_i: rows 0-7 = sup slot i%3, rows 8-15 = tgt.
        f32x4 accA = {0.f, 0.f, 0.f, 0.f};
        f32x4 accB = {0.f, 0.f, 0.f, 0.f};
        const char* rb = (const char*)((fr < 8) ? (sbuf[i % 3] + fr * 512)
                                                : (tbuf + (fr - 8) * 512));
        const int swz = (fr & 7) << 4;
        #pragma unroll
        for (int ch = 0; ch < 2; ++ch) {
            const int o  = wv * 256 + ch * 128 + kg * 32;      // byte off in 2KB row
            const int oa = (o & 0xC00) | ((o & 0x3FF) ^ swz);
            const int ob = ((o + 16) & 0xC00) | (((o + 16) & 0x3FF) ^ swz);
            const float4 f0 = *(const float4*)(rb + oa);
            const float4 f1 = *(const float4*)(rb + ob);
            union { unsigned int u[4]; short8 s8; } H, L;
            SPLIT2(f0.x, f0.y, H.u[0], L.u[0]);
            SPLIT2(f0.z, f0.w, H.u[1], L.u[1]);
            SPLIT2(f1.x, f1.y, H.u[2], L.u[2]);
            SPLIT2(f1.z, f1.w, H.u[3], L.u[3]);
            accA = __builtin_amdgcn_mfma_f32_16x16x32_bf16(H.s8, H.s8, accA, 0, 0, 0);
            accB = __builtin_amdgcn_mfma_f32_16x16x32_bf16(H.s8, L.s8, accB, 0, 0, 0);
            accB = __builtin_amdgcn_mfma_f32_16x16x32_bf16(L.s8, H.s8, accB, 0, 0, 0);
        }

        // Dump wave partials: D[(l>>4)*4+r][l&15] (verified convention).
        #pragma unroll
        for (int r = 0; r < 4; ++r)
            part[wv * 272 + (kg * 4 + r) * 17 + fr] = accA[r] + accB[r];
        asm volatile("s_waitcnt lgkmcnt(0)" ::: "memory");
        __builtin_amdgcn_s_barrier();
        __builtin_amdgcn_sched_barrier(0);

        if (tid < 256) {
            const int rr = tid >> 4, cc = tid & 15;
            float v = 0.f;
            #pragma unroll
            for (int w = 0; w < 8; ++w) v += part[w * 272 + rr * 17 + cc];
            const size_t p4 = (size_t)(((s0 + i) * NB + b) * 4 + kq);
            if (rr < 8) {
                if (cc >= 8)
                    ws[p4 * 100 + 36 + rr * 8 + (cc - 8)] = v;
                else if (cc >= rr)
                    ws[p4 * 100 + rr * 8 + cc - rr * (rr + 1) / 2] = v;
            } else if (sg == 0 && i == 0 && cc >= rr) {
                const int i8 = rr - 8, j8 = cc - 8;
                ws[WS_TGT + (size_t)(b * 4 + kq) * 36 + i8 * 8 + j8 - i8 * (i8 + 1) / 2] = v;
            }
        }
        asm volatile("s_waitcnt lgkmcnt(0)" ::: "memory");
        __builtin_amdgcn_s_barrier();
        __builtin_amdgcn_sched_barrier(0);
    }
}

// Kernel 2 (verbatim R7, validated): rebuild 16x16 synth Gram per pair from the
// 4 K-quarter partials, then the verified 16-lane Frechet solve, 16 pairs/blk.
__global__ __launch_bounds__(256) void solve_kernel(const float* __restrict__ ws,
                                                    float* __restrict__ out) {
    const int bid = blockIdx.x;
    const int tid = threadIdx.x;
    __shared__ float synth[16 * 256];

    for (int e = tid; e < 4096; e += 256) {
        const int pp = e >> 8, ij = e & 255;
        const int i = ij >> 4, j = ij & 15;
        const int p = bid * 16 + pp;
        const int b = p & (NB - 1);
        float v = 0.f;
        if (i < 8) {
            if (j < 8) {
                const int ii = i < j ? i : j, jj = i < j ? j : i;
                const int t36 = ii*8 + jj - ii*(ii+1)/2;
                #pragma unroll
                for (int kq = 0; kq < 4; ++kq) v += ws[(size_t)(p*4+kq)*100 + t36];
            } else {
                #pragma unroll
                for (int kq = 0; kq < 4; ++kq) v += ws[(size_t)(p*4+kq)*100 + 36 + i*8 + (j-8)];
            }
        } else if (j >= 8) {
            const int i8 = i - 8, j8 = j - 8;
            const int ii = i8 < j8 ? i8 : j8, jj = i8 < j8 ? j8 : i8;
            const int t36 = ii*8 + jj - ii*(ii+1)/2;
            #pragma unroll
            for (int kq = 0; kq < 4; ++kq) v += ws[WS_TGT + (size_t)(b*4+kq)*36 + t36];
        }
        synth[e] = v;
    }
    __syncthreads();

    const int pp = tid >> 4;
    const int t16 = tid & 15;
    const int p = bid * 16 + pp;
    const float* graw = synth + pp * 256;
    const int j = t16 & 7;
    const int base = t16 & 8;              // 0 = sup half, 8 = tgt half
    const int R = base + j;
    const int cb = base;

    const float invn_own = rsqrtf(fmaxf(graw[R * 16 + R], 1e-14f));
    float Grow[8];
    #pragma unroll
    for (int k = 0; k < 8; ++k) {
        const float invk = rsqrtf(fmaxf(graw[(cb + k) * 16 + (cb + k)], 1e-14f));
        Grow[k] = graw[R * 16 + cb + k] * invn_own * invk;
    }

    // mu0 = normalize(mean X^): a_k = rsqrt(sum G)
    float rs = 0.f;
    #pragma unroll
    for (int k = 0; k < 8; ++k) rs += Grow[k];
    rs += __shfl_xor(rs, 1, 8);
    rs += __shfl_xor(rs, 2, 8);
    rs += __shfl_xor(rs, 4, 8);
    float a_own = rsqrtf(fmaxf(rs, 6.4e-13f));
    float aAll[8];
    #pragma unroll
    for (int k = 0; k < 8; ++k) aAll[k] = a_own;

    for (int it = 0; it < NITER; ++it) {
        float dot = 0.f;
        #pragma unroll
        for (int k = 0; k < 8; ++k) dot = fmaf(Grow[k], aAll[k], dot);
        dot = fminf(fmaxf(dot, -1.f + 1e-6f), 1.f - 1e-6f);
        const float theta = acos_fast(dot);
        const float q = fmaf(-dot, dot, 1.0f);          // sin^2(theta)
        const float coef = (theta > 1e-4f) ? theta * rsqrtf(q) : 1.f;
        const float w = 0.125f * coef;
        float wAll[8];
        #pragma unroll
        for (int k = 0; k < 8; ++k) wAll[k] = __shfl(w, base + k, 16);
        float Gw = 0.f;
        #pragma unroll
        for (int k = 0; k < 8; ++k) Gw = fmaf(Grow[k], wAll[k], Gw);
        // two interleaved 8-lane reductions: cdavg = a^T G w, wGw = w^T G w
        float u1 = a_own * Gw, u2 = w * Gw;
        u1 += __shfl_xor(u1, 1, 8);  u2 += __shfl_xor(u2, 1, 8);
        u1 += __shfl_xor(u1, 2, 8);  u2 += __shfl_xor(u2, 2, 8);
        u1 += __shfl_xor(u1, 4, 8);  u2 += __shfl_xor(u2, 4, 8);
        const float cdavg = u1;
        const float vnsq = fmaxf(u2 - cdavg * cdavg, 0.f);   // ||v||^2
        const float vn = sqrtf(vnsq);
        const float rev = vn * 0.15915494309189535f;
        const float sinv = __builtin_amdgcn_sinf(rev);       // sin(vn)
        const float cosv = __builtin_amdgcn_cosf(rev);       // cos(vn)
        const float sinc = (vn > 1e-9f) ? sinv / vn : 1.f;
        // ||mu_new||^2 = cos^2 + sinc^2 * ||v||^2  (a^T G b = 0 algebraically)
        const float cn2 = fmaf(sinc * sinc, vnsq, cosv * cosv);
        const float rn = rsqrtf(fmaxf(cn2, 1e-14f));
        a_own = (cosv * a_own + sinc * fmaf(-cdavg, a_own, w)) * rn;
        #pragma unroll
        for (int k = 0; k < 8; ++k)
            aAll[k] = (cosv * aAll[k] + sinc * fmaf(-cdavg, aAll[k], wAll[k])) * rn;
    }

    // sim = sum_{j,l} ahat_sup_j * Craw[j][l] * ahat_tgt_l
    const float ahat = a_own * invn_own;
    float at[8];
    #pragma unroll
    for (int q2 = 0; q2 < 8; ++q2) at[q2] = __shfl(ahat, 8 + q2, 16);
    float tacc = 0.f;
    #pragma unroll
    for (int q2 = 0; q2 < 8; ++q2) tacc = fmaf(graw[j * 16 + 8 + q2], at[q2], tacc);
    float sim = ahat * tacc;
    sim += __shfl_xor(sim, 1, 8);
    sim += __shfl_xor(sim, 2, 8);
    sim += __shfl_xor(sim, 4, 8);
    if (t16 == 0) out[p] = sim;
}

extern "C" void kernel_launch(void* const* d_in, const int* in_sizes, int n_in,
                              void* d_out, int out_size, void* d_ws, size_t ws_size,
                              hipStream_t stream) {
    const float* sup = (const float*)d_in[0];   // [25,64,8,2048] f32
    const float* tgt = (const float*)d_in[1];   // [64,8,2048] f32
    float* ws = (float*)d_ws;                   // needs 649216 floats = 2.6 MB
    float* out = (float*)d_out;                 // [25,64] f32
    gram_kernel<<<NB * 4 * 5, 512, 0, stream>>>(sup, tgt, ws);
    solve_kernel<<<SOLVE_BLKS, 256, 0, stream>>>(ws, out);
}